// Round 11
// baseline (232.970 us; speedup 1.0000x reference)
//
#include <hip/hip_runtime.h>

typedef __bf16 bf16x8 __attribute__((ext_vector_type(8)));
typedef __bf16 bf16x4 __attribute__((ext_vector_type(4)));
typedef short  s16x8  __attribute__((ext_vector_type(8)));
typedef float  f32x4  __attribute__((ext_vector_type(4)));

#define MFMA16(a,b,c) __builtin_amdgcn_mfma_f32_16x16x32_bf16((a),(b),(c),0,0,0)

static constexpr float SCALE = 0.17677669529663687f;  // 1/sqrt(32)

__device__ __forceinline__ unsigned short f2b(float f){
  __bf16 h = (__bf16)f;
  return __builtin_bit_cast(unsigned short, h);
}
__device__ __forceinline__ bf16x8 ldfrag(const unsigned short* p){
  s16x8 v = *(const s16x8*)p;
  return __builtin_bit_cast(bf16x8, v);
}
__device__ __forceinline__ bf16x8 cvt8(const float* p){
  f32x4 a = *(const f32x4*)p;
  f32x4 b = *(const f32x4*)(p+4);
  bf16x8 r;
  r[0]=(__bf16)a[0]; r[1]=(__bf16)a[1]; r[2]=(__bf16)a[2]; r[3]=(__bf16)a[3];
  r[4]=(__bf16)b[0]; r[5]=(__bf16)b[1]; r[6]=(__bf16)b[2]; r[7]=(__bf16)b[3];
  return r;
}

// ---------------- projections: q/k/v = x @ W.T + b ----------------
// grid (M/16=256, 256/64=4, 3), block 256 (4 waves). Each wave: one 16x16 out tile.
// x tile (shared by all 4 waves) staged once in LDS as bf16, coalesced.
__global__ __launch_bounds__(256) void proj_kernel(
    const float* __restrict__ xq, const float* __restrict__ xk, const float* __restrict__ xv,
    const float* __restrict__ Wq, const float* __restrict__ bq,
    const float* __restrict__ Wk, const float* __restrict__ bk,
    const float* __restrict__ Wv, const float* __restrict__ bv,
    unsigned short* __restrict__ qo, unsigned short* __restrict__ ko,
    unsigned short* __restrict__ vT)
{
  const int z = blockIdx.z;
  const float* x    = (z==0) ? xq : (z==1 ? xk : xv);
  const float* W    = (z==0) ? Wq : (z==1 ? Wk : Wv);
  const float* bias = (z==0) ? bq : (z==1 ? bk : bv);
  const int tid = threadIdx.x, w = tid>>6, l = tid&63;
  const int m0 = blockIdx.x*16;
  const int n0 = blockIdx.y*64 + w*16;
  const int ra = l&15, ko8 = (l>>4)*8;

  __shared__ unsigned short xs[16*264];   // bf16 x tile, padded pitch
  #pragma unroll
  for(int i=0;i<4;++i){
    int chunk = tid + i*256;              // 0..1023
    int row = chunk>>6, c4 = (chunk&63)*4;
    f32x4 v = *(const f32x4*)(x + (m0+row)*256 + c4);
    ushort4 u; u.x=f2b(v[0]); u.y=f2b(v[1]); u.z=f2b(v[2]); u.w=f2b(v[3]);
    *(ushort4*)(&xs[row*264 + c4]) = u;
  }
  __syncthreads();

  f32x4 acc = {0.f,0.f,0.f,0.f};
  #pragma unroll
  for(int kk=0;kk<8;++kk){
    int kb = kk*32 + ko8;
    bf16x8 a   = ldfrag(&xs[ra*264 + kb]);
    bf16x8 bfr = cvt8(W + (n0+ra)*256 + kb);
    acc = MFMA16(a, bfr, acc);
  }
  const int col = l&15;
  const int n = n0 + col;
  const float bval = bias[n];

  __shared__ float vt[4][16][17];
  if(z < 2){
    unsigned short* out = (z==0) ? qo : ko;
    #pragma unroll
    for(int r=0;r<4;++r){
      int R = (l>>4)*4 + r, m = m0 + R;
      float val = acc[r] + bval;
      if(z==0) val *= SCALE;
      int bidx = m>>11, ls = m&2047, hh = n>>5, dh = n&31;
      out[(((long)(bidx*8+hh))*2048 + ls)*32 + dh] = f2b(val);
    }
  } else {
    #pragma unroll
    for(int r=0;r<4;++r){
      int R = (l>>4)*4 + r;
      vt[w][R][col] = acc[r] + bval;
    }
    __syncthreads();
    int bidx = m0>>11, hh = n0>>5, dh0 = n0&31, bh = bidx*8 + hh;
    int lsc = m0 & 2047;                 // per-batch column offset
    int dloc = l>>2, kloc = (l&3)*4;
    ushort4 pk;
    pk.x = f2b(vt[w][kloc+0][dloc]);
    pk.y = f2b(vt[w][kloc+1][dloc]);
    pk.z = f2b(vt[w][kloc+2][dloc]);
    pk.w = f2b(vt[w][kloc+3][dloc]);
    *reinterpret_cast<ushort4*>(vT + ((long)(bh*32 + dh0 + dloc))*2048 + lsc + kloc) = pk;
  }
}

// ---------------- fused attention ----------------
// grid (L/16=128, H=8, B=2), block 1024 (16 waves).
// r11: (1) P-store moved to the END (after last barrier) so its vmcnt drain
// rides out at s_endpgm instead of serializing at a barrier; e kept in 16
// bf16 regs through PV. (2) cross-barrier reg set shrunk (stream packed to
// bf16 immediately) so total arch+acc regs <= 64 -> 2 blocks/CU co-resident.
// Swizzle (short-index): sidx ^ ((row&7)<<3), consistent across all phases.
__global__ __launch_bounds__(1024) void attn_kernel(
    const unsigned short* __restrict__ qbf, const unsigned short* __restrict__ kbf,
    const unsigned short* __restrict__ vT,
    const float* __restrict__ sbias, const float* __restrict__ amask,
    float* __restrict__ Pout, float* __restrict__ ctx)
{
  __shared__ unsigned short sS[16*2048];  // 64KB bf16 score/e buffer (swizzled)
  __shared__ float linv[16];

  const int tid = threadIdx.x, w = tid>>6, l = tid&63;
  const int q0 = blockIdx.x*16;
  const int h = blockIdx.y, b = blockIdx.z;
  const int bh = b*8 + h;
  const long qkbase = (long)bh*2048*32;
  const long vbase  = (long)bh*32*2048;
  const long bmbase = ((long)bh*2048 + q0)*2048;
  const long rowbase = bmbase + (long)w*2048;   // this wave's softmax row
  const int ws = w*128;
  const int col = l&15, ko8 = (l>>4)*8, rg = (l>>4)*4;
  const int swq = (col&7)<<3;   // swizzle for row=col (QK^T store, PV read)
  const int sww = (w&7)<<3;     // swizzle for row=w   (softmax read/write)
  const f32x4 zero = {0.f,0.f,0.f,0.f};

  // ---- 1: QK^T swapped -> LDS. Lane: q-row=col, keys key0+rg..+3 -> b64 ----
  bf16x8 aq = ldfrag(qbf + qkbase + (long)(q0+col)*32 + ko8);
  #pragma unroll
  for(int t=0;t<8;++t){
    int key0 = ws + t*16;
    bf16x8 kf = ldfrag(kbf + qkbase + (long)(key0+col)*32 + ko8);
    f32x4 acc = MFMA16(kf, aq, zero);      // D[key, qrow]
    bf16x4 s4; s4[0]=(__bf16)acc[0]; s4[1]=(__bf16)acc[1];
    s4[2]=(__bf16)acc[2]; s4[3]=(__bf16)acc[3];
    *(bf16x4*)(&sS[col*2048 + ((key0+rg) ^ swq)]) = s4;
  }

  // ---- 2: bias+mask stream for row q0+w; pack to bf16 (16 regs, r9-validated) ----
  bf16x4 sbm[8];
  #pragma unroll
  for(int k=0;k<8;++k){
    long c = rowbase + k*256 + l*4;
    f32x4 b4 = *(const f32x4*)(sbias + c);
    f32x4 m4 = *(const f32x4*)(amask + c);
    f32x4 t = b4 + m4;
    bf16x4 t4; t4[0]=(__bf16)t[0]; t4[1]=(__bf16)t[1];
    t4[2]=(__bf16)t[2]; t4[3]=(__bf16)t[3];
    sbm[k] = t4;
  }
  __syncthreads();   // B1: sS complete

  // ---- 3: wave-local softmax over row q0+w ----
  float m = -1e30f;
  #pragma unroll
  for(int k=0;k<8;++k){
    int c = k*256 + l*4;
    bf16x4 r4 = *(const bf16x4*)(&sS[w*2048 + (c ^ sww)]);
    float t0=(float)r4[0]+(float)sbm[k][0];
    float t1=(float)r4[1]+(float)sbm[k][1];
    float t2=(float)r4[2]+(float)sbm[k][2];
    float t3=(float)r4[3]+(float)sbm[k][3];
    m = fmaxf(m, fmaxf(fmaxf(t0,t1), fmaxf(t2,t3)));
    bf16x4 t4; t4[0]=(__bf16)t0; t4[1]=(__bf16)t1;
    t4[2]=(__bf16)t2; t4[3]=(__bf16)t3;
    sbm[k] = t4;      // biased score, bf16 (r9-validated rounding)
  }
  #pragma unroll
  for(int d=1;d<64;d<<=1) m = fmaxf(m, __shfl_xor(m, d));
  float sum = 0.f;
  #pragma unroll
  for(int k=0;k<8;++k){
    float e0=__expf((float)sbm[k][0]-m); float e1=__expf((float)sbm[k][1]-m);
    float e2=__expf((float)sbm[k][2]-m); float e3=__expf((float)sbm[k][3]-m);
    sum += (e0+e1) + (e2+e3);
    bf16x4 e4; e4[0]=(__bf16)e0; e4[1]=(__bf16)e1;
    e4[2]=(__bf16)e2; e4[3]=(__bf16)e3;
    sbm[k] = e4;      // keep e in regs for the final P-store
    *(bf16x4*)(&sS[w*2048 + ((k*256 + l*4) ^ sww)]) = e4;
  }
  #pragma unroll
  for(int d=1;d<64;d<<=1) sum += __shfl_xor(sum, d);
  const float li = 1.0f/sum;
  if(l==0) linv[w] = li;
  __syncthreads();   // B2: e complete in sS

  // ---- 4: PV MFMA on key strip ws (A-frag = one b128 per 32-key chunk) ----
  f32x4 acc0 = zero, acc1 = zero;
  #pragma unroll
  for(int c4=0;c4<4;++c4){
    int kb = ws + c4*32 + ko8;
    bf16x8 pa = ldfrag(&sS[col*2048 + (kb ^ swq)]);
    bf16x8 v0 = ldfrag(vT + vbase + (long)col*2048 + kb);
    bf16x8 v1 = ldfrag(vT + vbase + (long)(16+col)*2048 + kb);
    acc0 = MFMA16(pa, v0, acc0);
    acc1 = MFMA16(pa, v1, acc1);
  }
  __syncthreads();   // B3: all PV reads of sS done

  // ---- 5: per-wave partial context into sS (as f32) ----
  float* sF = (float*)sS;   // 8192 f32 slots used of 16384
  #pragma unroll
  for(int r=0;r<4;++r){
    int R = rg + r;
    sF[w*512 + R*32 + col]      = acc0[r];
    sF[w*512 + R*32 + 16 + col] = acc1[r];
  }
  __syncthreads();   // B4

  // ---- 6: ctx write + P-store LAST (drain rides out at s_endpgm) ----
  if(tid < 512){
    int row = tid>>5, dh = tid&31;
    float ssum = 0.f;
    #pragma unroll
    for(int w2=0; w2<16; ++w2) ssum += sF[w2*512 + row*32 + dh];
    ctx[((long)b*2048 + q0 + row)*256 + h*32 + dh] = ssum * linv[row];
  }
  #pragma unroll
  for(int k=0;k<8;++k){
    f32x4 p;
    p[0]=(float)sbm[k][0]*li; p[1]=(float)sbm[k][1]*li;
    p[2]=(float)sbm[k][2]*li; p[3]=(float)sbm[k][3]*li;
    __builtin_nontemporal_store(p, (f32x4*)(Pout + rowbase + k*256 + l*4));
  }
}

// ---------------- output projection, in-place on out0 ----------------
// grid 4096/8=512 blocks, block 256 (4 waves), 8 rows/block (MFMA rows 8..15 discarded)
__global__ __launch_bounds__(256) void oproj_kernel(
    float* __restrict__ out0, const float* __restrict__ Wo, const float* __restrict__ bo)
{
  __shared__ unsigned short lct[8*264];
  const int tid = threadIdx.x, w = tid>>6, l = tid&63;
  const int m0 = blockIdx.x*8;
  #pragma unroll
  for(int i=0;i<2;++i){
    int chunk = tid + i*256;              // 0..511
    int row = chunk>>6, c4 = (chunk&63)*4;
    f32x4 v = *(const f32x4*)(out0 + (m0+row)*256 + c4);
    ushort4 u; u.x=f2b(v[0]); u.y=f2b(v[1]); u.z=f2b(v[2]); u.w=f2b(v[3]);
    *(ushort4*)(&lct[row*264 + c4]) = u;
  }
  __syncthreads();
  const int col = l&15, ko8 = (l>>4)*8, rg = (l>>4)*4;
  const int arow = col&7;
  #pragma unroll
  for(int nt=0;nt<4;++nt){
    int n0 = w*64 + nt*16;
    f32x4 acc = {0.f,0.f,0.f,0.f};
    #pragma unroll
    for(int kk=0;kk<8;++kk){
      int kb = kk*32 + ko8;
      bf16x8 a   = ldfrag(&lct[arow*264 + kb]);
      bf16x8 bfr = cvt8(Wo + (n0+col)*256 + kb);
      acc = MFMA16(a, bfr, acc);
    }
    float bv = bo[n0+col];
    if(rg < 8){
      #pragma unroll
      for(int r=0;r<4;++r){
        out0[(m0+rg+r)*256 + n0+col] = acc[r] + bv;
      }
    }
  }
}

extern "C" void kernel_launch(void* const* d_in, const int* in_sizes, int n_in,
                              void* d_out, int out_size, void* d_ws, size_t ws_size,
                              hipStream_t stream)
{
  const float* query = (const float*)d_in[0];
  const float* key   = (const float*)d_in[1];
  const float* value = (const float*)d_in[2];
  const float* sbias = (const float*)d_in[3];
  const float* amask = (const float*)d_in[4];
  const float* Wq = (const float*)d_in[5];
  const float* bq = (const float*)d_in[6];
  const float* Wk = (const float*)d_in[7];
  const float* bk = (const float*)d_in[8];
  const float* Wv = (const float*)d_in[9];
  const float* bv = (const float*)d_in[10];
  const float* Wo = (const float*)d_in[11];
  const float* bo = (const float*)d_in[12];

  float* out0 = (float*)d_out;                       // [2,2048,256]
  float* Pout = out0 + (size_t)2*2048*256;           // [2,8,2048,2048]

  unsigned short* qbf = (unsigned short*)d_ws;                 // [bh][L][32] bf16 (pre-scaled)
  unsigned short* kbf = qbf + (size_t)2*8*2048*32;             // [bh][L][32] bf16
  unsigned short* vTb = kbf + (size_t)2*8*2048*32;             // [bh][32][L] bf16 (transposed)

  proj_kernel<<<dim3(256,4,3), 256, 0, stream>>>(query,key,value,Wq,bq,Wk,bk,Wv,bv,qbf,kbf,vTb);
  attn_kernel<<<dim3(128,8,2), 1024, 0, stream>>>(qbf,kbf,vTb,sbias,amask,Pout,out0);
  oproj_kernel<<<dim3(512), 256, 0, stream>>>(out0,Wo,bo);
}

// Round 12
// 206.282 us; speedup vs baseline: 1.1294x; 1.1294x over previous
//
#include <hip/hip_runtime.h>

typedef __bf16 bf16x8 __attribute__((ext_vector_type(8)));
typedef __bf16 bf16x4 __attribute__((ext_vector_type(4)));
typedef short  s16x8  __attribute__((ext_vector_type(8)));
typedef float  f32x4  __attribute__((ext_vector_type(4)));

#define MFMA16(a,b,c) __builtin_amdgcn_mfma_f32_16x16x32_bf16((a),(b),(c),0,0,0)

static constexpr float SCALE = 0.17677669529663687f;  // 1/sqrt(32)

__device__ __forceinline__ unsigned short f2b(float f){
  __bf16 h = (__bf16)f;
  return __builtin_bit_cast(unsigned short, h);
}
__device__ __forceinline__ bf16x8 ldfrag(const unsigned short* p){
  s16x8 v = *(const s16x8*)p;
  return __builtin_bit_cast(bf16x8, v);
}
__device__ __forceinline__ bf16x8 cvt8(const float* p){
  f32x4 a = *(const f32x4*)p;
  f32x4 b = *(const f32x4*)(p+4);
  bf16x8 r;
  r[0]=(__bf16)a[0]; r[1]=(__bf16)a[1]; r[2]=(__bf16)a[2]; r[3]=(__bf16)a[3];
  r[4]=(__bf16)b[0]; r[5]=(__bf16)b[1]; r[6]=(__bf16)b[2]; r[7]=(__bf16)b[3];
  return r;
}

// Barrier that drains ONLY LDS ops (lgkmcnt). Global loads/stores (vmcnt)
// ride through -- the stream loads are wave-private and the P-stores need no
// barrier ordering. __syncthreads() would emit s_waitcnt vmcnt(0) and
// serialize the 256KB read delivery + 128KB P-store drain at every barrier
// (the m97-class stall; ~9us of the 20.7us block time).
__device__ __forceinline__ void bar_lgkm(){
  asm volatile("s_waitcnt lgkmcnt(0)" ::: "memory");
  __builtin_amdgcn_s_barrier();
  __builtin_amdgcn_sched_barrier(0);
}

// ---------------- projections: q/k/v = x @ W.T + b ----------------
// grid (M/16=256, 256/64=4, 3), block 256 (4 waves). Each wave: one 16x16 out tile.
// x tile (shared by all 4 waves) staged once in LDS as bf16, coalesced.
__global__ __launch_bounds__(256) void proj_kernel(
    const float* __restrict__ xq, const float* __restrict__ xk, const float* __restrict__ xv,
    const float* __restrict__ Wq, const float* __restrict__ bq,
    const float* __restrict__ Wk, const float* __restrict__ bk,
    const float* __restrict__ Wv, const float* __restrict__ bv,
    unsigned short* __restrict__ qo, unsigned short* __restrict__ ko,
    unsigned short* __restrict__ vT)
{
  const int z = blockIdx.z;
  const float* x    = (z==0) ? xq : (z==1 ? xk : xv);
  const float* W    = (z==0) ? Wq : (z==1 ? Wk : Wv);
  const float* bias = (z==0) ? bq : (z==1 ? bk : bv);
  const int tid = threadIdx.x, w = tid>>6, l = tid&63;
  const int m0 = blockIdx.x*16;
  const int n0 = blockIdx.y*64 + w*16;
  const int ra = l&15, ko8 = (l>>4)*8;

  __shared__ unsigned short xs[16*264];   // bf16 x tile, padded pitch
  #pragma unroll
  for(int i=0;i<4;++i){
    int chunk = tid + i*256;              // 0..1023
    int row = chunk>>6, c4 = (chunk&63)*4;
    f32x4 v = *(const f32x4*)(x + (m0+row)*256 + c4);
    ushort4 u; u.x=f2b(v[0]); u.y=f2b(v[1]); u.z=f2b(v[2]); u.w=f2b(v[3]);
    *(ushort4*)(&xs[row*264 + c4]) = u;
  }
  __syncthreads();

  f32x4 acc = {0.f,0.f,0.f,0.f};
  #pragma unroll
  for(int kk=0;kk<8;++kk){
    int kb = kk*32 + ko8;
    bf16x8 a   = ldfrag(&xs[ra*264 + kb]);
    bf16x8 bfr = cvt8(W + (n0+ra)*256 + kb);
    acc = MFMA16(a, bfr, acc);
  }
  const int col = l&15;
  const int n = n0 + col;
  const float bval = bias[n];

  __shared__ float vt[4][16][17];
  if(z < 2){
    unsigned short* out = (z==0) ? qo : ko;
    #pragma unroll
    for(int r=0;r<4;++r){
      int R = (l>>4)*4 + r, m = m0 + R;
      float val = acc[r] + bval;
      if(z==0) val *= SCALE;
      int bidx = m>>11, ls = m&2047, hh = n>>5, dh = n&31;
      out[(((long)(bidx*8+hh))*2048 + ls)*32 + dh] = f2b(val);
    }
  } else {
    #pragma unroll
    for(int r=0;r<4;++r){
      int R = (l>>4)*4 + r;
      vt[w][R][col] = acc[r] + bval;
    }
    __syncthreads();
    int bidx = m0>>11, hh = n0>>5, dh0 = n0&31, bh = bidx*8 + hh;
    int lsc = m0 & 2047;                 // per-batch column offset
    int dloc = l>>2, kloc = (l&3)*4;
    ushort4 pk;
    pk.x = f2b(vt[w][kloc+0][dloc]);
    pk.y = f2b(vt[w][kloc+1][dloc]);
    pk.z = f2b(vt[w][kloc+2][dloc]);
    pk.w = f2b(vt[w][kloc+3][dloc]);
    *reinterpret_cast<ushort4*>(vT + ((long)(bh*32 + dh0 + dloc))*2048 + lsc + kloc) = pk;
  }
}

// ---------------- fused attention ----------------
// grid (L/16=128, H=8, B=2), block 1024 (16 waves). r10 structure exactly,
// with __syncthreads() -> bar_lgkm() (lgkm-only barrier; see comment above).
// Swizzle (short-index): sidx ^ ((row&7)<<3), consistent across all phases.
__global__ __launch_bounds__(1024) void attn_kernel(
    const unsigned short* __restrict__ qbf, const unsigned short* __restrict__ kbf,
    const unsigned short* __restrict__ vT,
    const float* __restrict__ sbias, const float* __restrict__ amask,
    float* __restrict__ Pout, float* __restrict__ ctx)
{
  __shared__ unsigned short sS[16*2048];  // 64KB bf16 score/e buffer (swizzled)
  __shared__ float linv[16];

  const int tid = threadIdx.x, w = tid>>6, l = tid&63;
  const int q0 = blockIdx.x*16;
  const int h = blockIdx.y, b = blockIdx.z;
  const int bh = b*8 + h;
  const long qkbase = (long)bh*2048*32;
  const long vbase  = (long)bh*32*2048;
  const long bmbase = ((long)bh*2048 + q0)*2048;
  const long rowbase = bmbase + (long)w*2048;   // this wave's softmax row
  const int ws = w*128;
  const int col = l&15, ko8 = (l>>4)*8, rg = (l>>4)*4;
  const int swq = (col&7)<<3;   // swizzle for row=col (QK^T store, PV read)
  const int sww = (w&7)<<3;     // swizzle for row=w   (softmax read/write)
  const f32x4 zero = {0.f,0.f,0.f,0.f};

  // ---- 1: QK^T swapped -> LDS. Lane: q-row=col, keys key0+rg..+3 -> b64 ----
  bf16x8 aq = ldfrag(qbf + qkbase + (long)(q0+col)*32 + ko8);
  #pragma unroll
  for(int t=0;t<8;++t){
    int key0 = ws + t*16;
    bf16x8 kf = ldfrag(kbf + qkbase + (long)(key0+col)*32 + ko8);
    f32x4 acc = MFMA16(kf, aq, zero);      // D[key, qrow]
    bf16x4 s4; s4[0]=(__bf16)acc[0]; s4[1]=(__bf16)acc[1];
    s4[2]=(__bf16)acc[2]; s4[3]=(__bf16)acc[3];
    *(bf16x4*)(&sS[col*2048 + ((key0+rg) ^ swq)]) = s4;
  }

  // ---- 2: bias+mask stream for row q0+w (rides through B1's barrier) ----
  f32x4 s[8];
  #pragma unroll
  for(int k=0;k<8;++k){
    long c = rowbase + k*256 + l*4;
    f32x4 b4 = __builtin_nontemporal_load((const f32x4*)(sbias + c));
    f32x4 m4 = __builtin_nontemporal_load((const f32x4*)(amask + c));
    s[k] = b4 + m4;
  }
  bar_lgkm();   // B1: sS complete (lgkm only; stream loads stay in flight)

  // ---- 3: wave-local softmax over row q0+w (dense b64 reads) ----
  float m = -1e30f;
  #pragma unroll
  for(int k=0;k<8;++k){
    int c = k*256 + l*4;
    bf16x4 r4 = *(const bf16x4*)(&sS[w*2048 + (c ^ sww)]);
    s[k][0]+=(float)r4[0]; s[k][1]+=(float)r4[1];
    s[k][2]+=(float)r4[2]; s[k][3]+=(float)r4[3];
    m = fmaxf(m, fmaxf(fmaxf(s[k][0],s[k][1]), fmaxf(s[k][2],s[k][3])));
  }
  #pragma unroll
  for(int d=1;d<64;d<<=1) m = fmaxf(m, __shfl_xor(m, d));
  float sum = 0.f;
  #pragma unroll
  for(int k=0;k<8;++k){
    s[k][0]=__expf(s[k][0]-m); s[k][1]=__expf(s[k][1]-m);
    s[k][2]=__expf(s[k][2]-m); s[k][3]=__expf(s[k][3]-m);
    sum += (s[k][0]+s[k][1]) + (s[k][2]+s[k][3]);
  }
  #pragma unroll
  for(int d=1;d<64;d<<=1) sum += __shfl_xor(sum, d);
  const float li = 1.0f/sum;
  if(l==0) linv[w] = li;

  // ---- 4: write P (f32, nontemporal; drain rides through B2..endpgm) + e (bf16) ----
  #pragma unroll
  for(int k=0;k<8;++k){
    int c = k*256 + l*4;
    f32x4 p; p[0]=s[k][0]*li; p[1]=s[k][1]*li; p[2]=s[k][2]*li; p[3]=s[k][3]*li;
    __builtin_nontemporal_store(p, (f32x4*)(Pout + rowbase + c));
    bf16x4 e4; e4[0]=(__bf16)s[k][0]; e4[1]=(__bf16)s[k][1];
    e4[2]=(__bf16)s[k][2]; e4[3]=(__bf16)s[k][3];
    *(bf16x4*)(&sS[w*2048 + (c ^ sww)]) = e4;
  }
  bar_lgkm();   // B2: e complete in sS (P-stores stay in flight)

  // ---- 5: PV MFMA on key strip ws (A-frag = one b128 per 32-key chunk) ----
  f32x4 acc0 = zero, acc1 = zero;
  #pragma unroll
  for(int c4=0;c4<4;++c4){
    int kb = ws + c4*32 + ko8;
    bf16x8 pa = ldfrag(&sS[col*2048 + (kb ^ swq)]);
    bf16x8 v0 = ldfrag(vT + vbase + (long)col*2048 + kb);
    bf16x8 v1 = ldfrag(vT + vbase + (long)(16+col)*2048 + kb);
    acc0 = MFMA16(pa, v0, acc0);
    acc1 = MFMA16(pa, v1, acc1);
  }
  bar_lgkm();   // B3: all PV reads of sS returned (lgkm drained per wave)

  // ---- 6: per-wave partial context into sS (as f32) ----
  float* sF = (float*)sS;   // 8192 f32 slots used of 16384
  #pragma unroll
  for(int r=0;r<4;++r){
    int R = rg + r;
    sF[w*512 + R*32 + col]      = acc0[r];
    sF[w*512 + R*32 + 16 + col] = acc1[r];
  }
  bar_lgkm();   // B4

  // ---- 7: reduce across waves, write context ----
  if(tid < 512){
    int row = tid>>5, dh = tid&31;
    float ssum = 0.f;
    #pragma unroll
    for(int w2=0; w2<16; ++w2) ssum += sF[w2*512 + row*32 + dh];
    ctx[((long)b*2048 + q0 + row)*256 + h*32 + dh] = ssum * linv[row];
  }
}

// ---------------- output projection, in-place on out0 ----------------
// grid 4096/8=512 blocks, block 256 (4 waves), 8 rows/block (MFMA rows 8..15 discarded)
__global__ __launch_bounds__(256) void oproj_kernel(
    float* __restrict__ out0, const float* __restrict__ Wo, const float* __restrict__ bo)
{
  __shared__ unsigned short lct[8*264];
  const int tid = threadIdx.x, w = tid>>6, l = tid&63;
  const int m0 = blockIdx.x*8;
  #pragma unroll
  for(int i=0;i<2;++i){
    int chunk = tid + i*256;              // 0..511
    int row = chunk>>6, c4 = (chunk&63)*4;
    f32x4 v = *(const f32x4*)(out0 + (m0+row)*256 + c4);
    ushort4 u; u.x=f2b(v[0]); u.y=f2b(v[1]); u.z=f2b(v[2]); u.w=f2b(v[3]);
    *(ushort4*)(&lct[row*264 + c4]) = u;
  }
  __syncthreads();
  const int col = l&15, ko8 = (l>>4)*8, rg = (l>>4)*4;
  const int arow = col&7;
  #pragma unroll
  for(int nt=0;nt<4;++nt){
    int n0 = w*64 + nt*16;
    f32x4 acc = {0.f,0.f,0.f,0.f};
    #pragma unroll
    for(int kk=0;kk<8;++kk){
      int kb = kk*32 + ko8;
      bf16x8 a   = ldfrag(&lct[arow*264 + kb]);
      bf16x8 bfr = cvt8(Wo + (n0+col)*256 + kb);
      acc = MFMA16(a, bfr, acc);
    }
    float bv = bo[n0+col];
    if(rg < 8){
      #pragma unroll
      for(int r=0;r<4;++r){
        out0[(m0+rg+r)*256 + n0+col] = acc[r] + bv;
      }
    }
  }
}

extern "C" void kernel_launch(void* const* d_in, const int* in_sizes, int n_in,
                              void* d_out, int out_size, void* d_ws, size_t ws_size,
                              hipStream_t stream)
{
  const float* query = (const float*)d_in[0];
  const float* key   = (const float*)d_in[1];
  const float* value = (const float*)d_in[2];
  const float* sbias = (const float*)d_in[3];
  const float* amask = (const float*)d_in[4];
  const float* Wq = (const float*)d_in[5];
  const float* bq = (const float*)d_in[6];
  const float* Wk = (const float*)d_in[7];
  const float* bk = (const float*)d_in[8];
  const float* Wv = (const float*)d_in[9];
  const float* bv = (const float*)d_in[10];
  const float* Wo = (const float*)d_in[11];
  const float* bo = (const float*)d_in[12];

  float* out0 = (float*)d_out;                       // [2,2048,256]
  float* Pout = out0 + (size_t)2*2048*256;           // [2,8,2048,2048]

  unsigned short* qbf = (unsigned short*)d_ws;                 // [bh][L][32] bf16 (pre-scaled)
  unsigned short* kbf = qbf + (size_t)2*8*2048*32;             // [bh][L][32] bf16
  unsigned short* vTb = kbf + (size_t)2*8*2048*32;             // [bh][32][L] bf16 (transposed)

  proj_kernel<<<dim3(256,4,3), 256, 0, stream>>>(query,key,value,Wq,bq,Wk,bk,Wv,bv,qbf,kbf,vTb);
  attn_kernel<<<dim3(128,8,2), 1024, 0, stream>>>(qbf,kbf,vTb,sbias,amask,Pout,out0);
  oproj_kernel<<<dim3(512), 256, 0, stream>>>(out0,Wo,bo);
}